// Round 19
// baseline (98.253 us; speedup 1.0000x reference)
//
#include <hip/hip_runtime.h>
#include <hip/hip_bf16.h>

#define N_SRCC 50000
#define N_DSTC 50000
#define N_EDG 800000
#define NBUK 500
#define DPB 100        // dst nodes per bucket
#define BCAP 2048      // fixed bucket capacity (mean 1600, +11 sigma)
#define EPB 3334       // edges per partition block
#define NPB 240        // ceil(N_EDG/EPB)
#define HSB 196        // ceil(50000/256) hs gemm blocks (256-row tiles)
#define ERB 196        // er gemm blocks

typedef __attribute__((ext_vector_type(8))) short bf16x8;
typedef __attribute__((ext_vector_type(4))) float f32x4;
typedef __attribute__((ext_vector_type(8))) unsigned short us8;

__device__ inline short f2bf(float x) {
  __hip_bfloat16 b = __float2bfloat16(x);
  return *reinterpret_cast<short*>(&b);
}
__device__ inline float bf2f(unsigned hi16) {
  union { unsigned u; float f; } c; c.u = hi16 << 16; return c.f;
}

// ---------------- fold: U, Cc, W_src->bf16, U_dst->bf16 (16 rows), zero bCur
__global__ void fold_kernel(const float* __restrict__ Wsrc, const float* __restrict__ bsrc,
                            const float* __restrict__ Wdst, const float* __restrict__ bdst,
                            const float* __restrict__ attn,
                            float* __restrict__ U, float* __restrict__ Cc,
                            short* __restrict__ Wbf, short* __restrict__ Ubf,
                            int* __restrict__ bCur) {
  int t = blockIdx.x * blockDim.x + threadIdx.x;   // 4096 threads
  if (t < 4096) {
    int side = t >> 11;
    int r = (t >> 8) & 7;
    int c = t & 255;
    const float* W = side ? Wdst : Wsrc;
    float s = 0.f;
    #pragma unroll
    for (int d = 0; d < 16; d++)
      s += attn[r*32 + side*16 + d] * W[(r*16 + d)*256 + c];
    U[t] = s;
    if (side == 1) Ubf[r*256 + c] = f2bf(s);   // rows 0..7 = U_dst
    else           Ubf[2048 + t]  = 0;          // rows 8..15 = zero pad
    const float4* p = (const float4*)&Wsrc[t*8];
    float4 v0 = p[0], v1 = p[1];
    bf16x8 w;
    w[0]=f2bf(v0.x); w[1]=f2bf(v0.y); w[2]=f2bf(v0.z); w[3]=f2bf(v0.w);
    w[4]=f2bf(v1.x); w[5]=f2bf(v1.y); w[6]=f2bf(v1.z); w[7]=f2bf(v1.w);
    *(bf16x8*)&Wbf[t*8] = w;
  }
  if (t < 16) {
    int side = t >> 3, r = t & 7;
    const float* b = side ? bdst : bsrc;
    float s = 0.f;
    #pragma unroll
    for (int d = 0; d < 16; d++) s += attn[r*32 + side*16 + d] * b[r*16 + d];
    Cc[t] = s;
  }
  if (t < NBUK) bCur[t] = 0;
}

// ---------------- edge partition (standalone, 512 threads)
__global__ __launch_bounds__(512) void partition_k(
    const int* __restrict__ src, const int* __restrict__ dst,
    int* __restrict__ bCur, unsigned* __restrict__ bData) {
  __shared__ int h[NBUK];
  __shared__ int cur[NBUK];
  int b = blockIdx.x;
  int tid = threadIdx.x;
  for (int i = tid; i < NBUK; i += 512) h[i] = 0;
  __syncthreads();
  int start = b * EPB;
  int end = min(start + EPB, N_EDG);
  for (int e = start + tid; e < end; e += 512)
    atomicAdd(&h[dst[e] / DPB], 1);
  __syncthreads();
  for (int i = tid; i < NBUK; i += 512) {
    int c = h[i];
    cur[i] = c ? atomicAdd(&bCur[i], c) : 0;
  }
  __syncthreads();
  for (int e = start + tid; e < end; e += 512) {
    int d = dst[e], bk = d / DPB;
    int pos = atomicAdd(&cur[bk], 1);
    if (pos < BCAP)
      bData[(size_t)bk*BCAP + pos] = (unsigned)src[e] | ((unsigned)(d - bk*DPB) << 16);
  }
}

// ---------------- hs512: 256-row tile, 8 waves (4x2), fused el (standalone)
__global__ __launch_bounds__(512) void hs512(
    const float* __restrict__ A, const short* __restrict__ Wbf,
    const float* __restrict__ bias, const float* __restrict__ attn,
    __hip_bfloat16* __restrict__ C, float* __restrict__ el) {
  __shared__ short As[256][40];
  __shared__ short Bs[128][40];
  int t = threadIdx.x;
  int lane = t & 63, wid = t >> 6;
  int wr = wid >> 1, wc = wid & 1;
  int row0 = blockIdx.x * 256;
  int lr = lane & 15, lk = lane >> 4;
  int sr = t >> 1, skq = (t & 1) * 16;
  int br = t >> 2, bq = (t & 3) * 8;
  f32x4 acc[4][4] = {};

  for (int k0 = 0; k0 < 256; k0 += 32) {
    {
      int gr = row0 + sr;
      float4 v0 = {}, v1 = {}, v2 = {}, v3 = {};
      if (gr < N_SRCC) {
        const float4* p = (const float4*)&A[(size_t)gr*256 + k0 + skq];
        v0 = p[0]; v1 = p[1]; v2 = p[2]; v3 = p[3];
      }
      bf16x8 t0, t1;
      t0[0]=f2bf(v0.x); t0[1]=f2bf(v0.y); t0[2]=f2bf(v0.z); t0[3]=f2bf(v0.w);
      t0[4]=f2bf(v1.x); t0[5]=f2bf(v1.y); t0[6]=f2bf(v1.z); t0[7]=f2bf(v1.w);
      t1[0]=f2bf(v2.x); t1[1]=f2bf(v2.y); t1[2]=f2bf(v2.z); t1[3]=f2bf(v2.w);
      t1[4]=f2bf(v3.x); t1[5]=f2bf(v3.y); t1[6]=f2bf(v3.z); t1[7]=f2bf(v3.w);
      *(bf16x8*)&As[sr][skq]     = t0;
      *(bf16x8*)&As[sr][skq + 8] = t1;
    }
    *(bf16x8*)&Bs[br][bq] = *(const bf16x8*)&Wbf[br*256 + k0 + bq];
    __syncthreads();
    bf16x8 af[4], bfr[4];
    #pragma unroll
    for (int m = 0; m < 4; m++)
      af[m] = *(const bf16x8*)&As[wr*64 + m*16 + lr][lk*8];
    #pragma unroll
    for (int n = 0; n < 4; n++)
      bfr[n] = *(const bf16x8*)&Bs[wc*64 + n*16 + lr][lk*8];
    #pragma unroll
    for (int m = 0; m < 4; m++)
      #pragma unroll
      for (int n = 0; n < 4; n++)
        acc[m][n] = __builtin_amdgcn_mfma_f32_16x16x32_bf16(af[m], bfr[n], acc[m][n], 0, 0, 0);
    __syncthreads();
  }
  #pragma unroll
  for (int m = 0; m < 4; m++) {
    int r0 = row0 + wr*64 + m*16 + lk*4;
    #pragma unroll
    for (int n = 0; n < 4; n++) {
      int col = wc*64 + n*16 + lr;
      int h = wc*4 + n;
      float bv = bias[col];
      float al = attn[h*32 + lr];
      #pragma unroll
      for (int j = 0; j < 4; j++) {
        int gr = r0 + j;
        float hv = acc[m][n][j] + bv;
        if (gr < N_SRCC) C[(size_t)gr*128 + col] = __float2bfloat16(hv);
        float p = hv * al;
        p += __shfl_xor(p, 1); p += __shfl_xor(p, 2);
        p += __shfl_xor(p, 4); p += __shfl_xor(p, 8);
        if (lr == 0 && gr < N_SRCC) el[gr*8 + h] = p;
      }
    }
  }
}

// ---------------- ersort: blocks [0,ERB) er-gemm (256-row); [ERB,ERB+NBUK) sort
__global__ __launch_bounds__(512) void ersort(
    const float* __restrict__ feat_dst, const short* __restrict__ Ubf,
    const float* __restrict__ Cc, float* __restrict__ er,
    const unsigned* __restrict__ bData, const int* __restrict__ bCur,
    int* __restrict__ offS, int* __restrict__ offE,
    unsigned short* __restrict__ srcS) {
  __shared__ __align__(16) char smem[29184];
  int b = blockIdx.x;
  int t = threadIdx.x;

  if (b < ERB) {
    // ---- er gemm: 256-row tile, 8 waves of 32 rows; Bu resident ----
    short (*As)[40]  = (short(*)[40])smem;             // 256x40 = 20480 B
    short (*Bu)[264] = (short(*)[264])(smem + 20480);  // 16x264*2 = 8448 B
    int lane = t & 63, w = t >> 6;
    int row0 = b * 256;
    int lr = lane & 15, lk = lane >> 4;
    int sr = t >> 1, skq = (t & 1) * 16;
    {
      int r = t >> 5, ck = t & 31;      // 512 threads = 16 rows x 32 chunks
      *(bf16x8*)&Bu[r][ck*8] = *(const bf16x8*)&Ubf[r*256 + ck*8];
    }
    f32x4 acc[2] = {};
    for (int k0 = 0; k0 < 256; k0 += 32) {
      {
        int gr = row0 + sr;
        float4 v0 = {}, v1 = {}, v2 = {}, v3 = {};
        if (gr < N_DSTC) {
          const float4* p = (const float4*)&feat_dst[(size_t)gr*256 + k0 + skq];
          v0 = p[0]; v1 = p[1]; v2 = p[2]; v3 = p[3];
        }
        bf16x8 t0, t1;
        t0[0]=f2bf(v0.x); t0[1]=f2bf(v0.y); t0[2]=f2bf(v0.z); t0[3]=f2bf(v0.w);
        t0[4]=f2bf(v1.x); t0[5]=f2bf(v1.y); t0[6]=f2bf(v1.z); t0[7]=f2bf(v1.w);
        t1[0]=f2bf(v2.x); t1[1]=f2bf(v2.y); t1[2]=f2bf(v2.z); t1[3]=f2bf(v2.w);
        t1[4]=f2bf(v3.x); t1[5]=f2bf(v3.y); t1[6]=f2bf(v3.z); t1[7]=f2bf(v3.w);
        *(bf16x8*)&As[sr][skq]     = t0;
        *(bf16x8*)&As[sr][skq + 8] = t1;
      }
      __syncthreads();
      bf16x8 bu = *(const bf16x8*)&Bu[lr][k0 + lk*8];
      #pragma unroll
      for (int m = 0; m < 2; m++) {
        bf16x8 af = *(const bf16x8*)&As[w*32 + m*16 + lr][lk*8];
        acc[m] = __builtin_amdgcn_mfma_f32_16x16x32_bf16(af, bu, acc[m], 0, 0, 0);
      }
      __syncthreads();
    }
    if (lr < 8) {
      float cb = Cc[8 + lr];
      #pragma unroll
      for (int m = 0; m < 2; m++) {
        int r0 = row0 + w*32 + m*16 + lk*4;
        #pragma unroll
        for (int j = 0; j < 4; j++) {
          int gr2 = r0 + j;
          if (gr2 < N_DSTC) er[gr2*8 + lr] = acc[m][j] + cb;
        }
      }
    }
    return;
  }

  // ---- per-bucket counting sort (100 bins) ----
  {
    int* hist = (int*)smem;                 // 100 ints
    int* s    = hist + DPB;                 // 128 ints
    int* cur  = s + 128;                    // 100 ints
    int bb = b - ERB;
    int cnt = min(bCur[bb], BCAP);
    int base = bb * BCAP;
    for (int i = t; i < DPB; i += 512) hist[i] = 0;
    __syncthreads();
    for (int e = t; e < cnt; e += 512) atomicAdd(&hist[bData[base + e] >> 16], 1);
    __syncthreads();
    if (t < 128) s[t] = (t < DPB) ? hist[t] : 0;
    __syncthreads();
    for (int d = 1; d < 128; d <<= 1) {
      int v = (t < 128 && t >= d) ? s[t - d] : 0;
      __syncthreads();
      if (t < 128) s[t] += v;
      __syncthreads();
    }
    if (t < DPB) {
      int excl = s[t] - hist[t];
      cur[t] = excl;
      offS[bb * DPB + t] = base + excl;
      offE[bb * DPB + t] = base + excl + hist[t];
    }
    __syncthreads();
    for (int e = t; e < cnt; e += 512) {
      unsigned ent = bData[base + e];
      int pos = atomicAdd(&cur[ent >> 16], 1);
      srcS[base + pos] = (unsigned short)(ent & 0xffffu);
    }
  }
}

// ---------------- aggregation: one wave per 2 dst lists, 16 edges in flight
__global__ __launch_bounds__(256) void aggregate(
    const __hip_bfloat16* __restrict__ hs, const float* __restrict__ el,
    const float* __restrict__ er, const int* __restrict__ offS,
    const int* __restrict__ offE, const unsigned short* __restrict__ srcS,
    float* __restrict__ out) {
  int w = threadIdx.x >> 6;
  int lane = threadIdx.x & 63;
  int jA = blockIdx.x * 8 + w;
  int jB = jA + 4;
  int g = lane >> 4;
  int q = lane & 15;
  int h = q >> 1;
  int e0a = offS[jA], remA = offE[jA] - e0a;
  int e0b = offS[jB], remB = offE[jB] - e0b;
  float erA = er[jA*8 + h];
  float erB = er[jB*8 + h];
  float accA[8] = {}, accB[8] = {};
  float denA = 0.f, denB = 0.f;

  #define AGG_BODY(E, ERH, ACC, DEN) { \
    int s = srcS[E]; \
    float ev = el[s*8 + h] + ERH; \
    ev = ev >= 0.f ? ev : 0.2f * ev; \
    float wg = __expf(ev); \
    DEN += wg; \
    us8 hv = *(const us8*)&hs[(size_t)s*128 + q*8]; \
    _Pragma("unroll") \
    for (int c = 0; c < 8; c++) { \
      ACC[c] = fmaf(wg, bf2f((unsigned)hv[c]), ACC[c]); \
    } \
  }

  int ka = 0, kb = 0;
  while (ka + 8 <= remA && kb + 8 <= remB) {
    AGG_BODY(e0a + ka + g, erA, accA, denA);
    AGG_BODY(e0b + kb + g, erB, accB, denB);
    AGG_BODY(e0a + ka + 4 + g, erA, accA, denA);
    AGG_BODY(e0b + kb + 4 + g, erB, accB, denB);
    ka += 8; kb += 8;
  }
  while (ka + 4 <= remA && kb + 4 <= remB) {
    AGG_BODY(e0a + ka + g, erA, accA, denA);
    AGG_BODY(e0b + kb + g, erB, accB, denB);
    ka += 4; kb += 4;
  }
  while (ka + 4 <= remA) { AGG_BODY(e0a + ka + g, erA, accA, denA); ka += 4; }
  while (kb + 4 <= remB) { AGG_BODY(e0b + kb + g, erB, accB, denB); kb += 4; }
  if (ka + g < remA) AGG_BODY(e0a + ka + g, erA, accA, denA);
  if (kb + g < remB) AGG_BODY(e0b + kb + g, erB, accB, denB);
  #undef AGG_BODY

  #pragma unroll
  for (int c = 0; c < 8; c++) {
    accA[c] += __shfl_xor(accA[c], 16); accA[c] += __shfl_xor(accA[c], 32);
    accB[c] += __shfl_xor(accB[c], 16); accB[c] += __shfl_xor(accB[c], 32);
  }
  denA += __shfl_xor(denA, 16); denA += __shfl_xor(denA, 32);
  denB += __shfl_xor(denB, 16); denB += __shfl_xor(denB, 32);
  if (g == 0) {
    float invA = (remA > 0) ? 1.f / denA : 0.f;
    float invB = (remB > 0) ? 1.f / denB : 0.f;
    float4 r0, r1;
    r0.x = accA[0]*invA; r0.y = accA[1]*invA; r0.z = accA[2]*invA; r0.w = accA[3]*invA;
    r1.x = accA[4]*invA; r1.y = accA[5]*invA; r1.z = accA[6]*invA; r1.w = accA[7]*invA;
    *(float4*)&out[(size_t)jA*128 + q*8]     = r0;
    *(float4*)&out[(size_t)jA*128 + q*8 + 4] = r1;
    r0.x = accB[0]*invB; r0.y = accB[1]*invB; r0.z = accB[2]*invB; r0.w = accB[3]*invB;
    r1.x = accB[4]*invB; r1.y = accB[5]*invB; r1.z = accB[6]*invB; r1.w = accB[7]*invB;
    *(float4*)&out[(size_t)jB*128 + q*8]     = r0;
    *(float4*)&out[(size_t)jB*128 + q*8 + 4] = r1;
  }
}

extern "C" void kernel_launch(void* const* d_in, const int* in_sizes, int n_in,
                              void* d_out, int out_size, void* d_ws, size_t ws_size,
                              hipStream_t stream) {
  const float* feat_src = (const float*)d_in[0];
  const float* feat_dst = (const float*)d_in[1];
  const float* W_src = (const float*)d_in[2];
  const float* b_src = (const float*)d_in[3];
  const float* W_dst = (const float*)d_in[4];
  const float* b_dst = (const float*)d_in[5];
  const float* attn  = (const float*)d_in[6];
  const int* src_idx = (const int*)d_in[7];
  const int* dst_idx = (const int*)d_in[8];
  float* out = (float*)d_out;

  __hip_bfloat16* hs_bf = (__hip_bfloat16*)d_ws;        // 12.8 MB
  float* el = (float*)(hs_bf + (size_t)N_SRCC*128);     // 400,000 f
  float* er = el + (size_t)N_SRCC*8;                    // 400,000 f
  float* U  = er + (size_t)N_DSTC*8;                    // 4096 f
  float* Cc = U + 4096;                                 // 16 f
  short* Wbf = (short*)(Cc + 16);                       // 32768 bf16
  short* Ubf = Wbf + 32768;                             // 4096 bf16 (16x256)
  int* bCur  = (int*)(Ubf + 4096);                      // 500 i
  int* offS  = bCur + NBUK;                             // 50000 i
  int* offE  = offS + N_DSTC;                           // 50000 i
  unsigned* bData = (unsigned*)(offE + N_DSTC);         // 500*2048 u32
  unsigned short* srcS = (unsigned short*)(bData + (size_t)NBUK*BCAP);

  fold_kernel<<<16, 256, 0, stream>>>(W_src, b_src, W_dst, b_dst, attn, U, Cc,
                                      Wbf, Ubf, bCur);
  partition_k<<<NPB, 512, 0, stream>>>(src_idx, dst_idx, bCur, bData);
  hs512<<<HSB, 512, 0, stream>>>(feat_src, Wbf, b_src, attn, hs_bf, el);
  ersort<<<ERB + NBUK, 512, 0, stream>>>(feat_dst, Ubf, Cc, er,
                                         bData, bCur, offS, offE, srcS);
  aggregate<<<(N_DSTC + 7)/8, 256, 0, stream>>>(hs_bf, el, er, offS, offE, srcS, out);
}

// Round 20
// 81.084 us; speedup vs baseline: 1.2117x; 1.2117x over previous
//
#include <hip/hip_runtime.h>
#include <hip/hip_bf16.h>

#define N_SRCC 50000
#define N_DSTC 50000
#define N_EDG 800000
#define NBUK 500
#define DPB 100        // dst nodes per bucket
#define BCAP 2048      // fixed bucket capacity (mean 1600, +11 sigma)
#define EPB 3334       // edges per partition block
#define NPB 240        // ceil(N_EDG/EPB)
#define GEMB 391       // ceil(50000/128) gemm blocks (each role)

typedef __attribute__((ext_vector_type(8))) short bf16x8;
typedef __attribute__((ext_vector_type(4))) float f32x4;
typedef __attribute__((ext_vector_type(8))) unsigned short us8;

__device__ inline short f2bf(float x) {
  __hip_bfloat16 b = __float2bfloat16(x);
  return *reinterpret_cast<short*>(&b);
}
__device__ inline float bf2f(unsigned hi16) {
  union { unsigned u; float f; } c; c.u = hi16 << 16; return c.f;
}

// ---------------- fold: U, Cc, W_src->bf16, U_dst->bf16 (16 rows), zero bCur
__global__ void fold_kernel(const float* __restrict__ Wsrc, const float* __restrict__ bsrc,
                            const float* __restrict__ Wdst, const float* __restrict__ bdst,
                            const float* __restrict__ attn,
                            float* __restrict__ U, float* __restrict__ Cc,
                            short* __restrict__ Wbf, short* __restrict__ Ubf,
                            int* __restrict__ bCur) {
  int t = blockIdx.x * blockDim.x + threadIdx.x;   // 4096 threads
  if (t < 4096) {
    int side = t >> 11;
    int r = (t >> 8) & 7;
    int c = t & 255;
    const float* W = side ? Wdst : Wsrc;
    float s = 0.f;
    #pragma unroll
    for (int d = 0; d < 16; d++)
      s += attn[r*32 + side*16 + d] * W[(r*16 + d)*256 + c];
    U[t] = s;
    if (side == 1) Ubf[r*256 + c] = f2bf(s);   // rows 0..7 = U_dst
    else           Ubf[2048 + t]  = 0;          // rows 8..15 = zero pad
    const float4* p = (const float4*)&Wsrc[t*8];
    float4 v0 = p[0], v1 = p[1];
    bf16x8 w;
    w[0]=f2bf(v0.x); w[1]=f2bf(v0.y); w[2]=f2bf(v0.z); w[3]=f2bf(v0.w);
    w[4]=f2bf(v1.x); w[5]=f2bf(v1.y); w[6]=f2bf(v1.z); w[7]=f2bf(v1.w);
    *(bf16x8*)&Wbf[t*8] = w;
  }
  if (t < 16) {
    int side = t >> 3, r = t & 7;
    const float* b = side ? bdst : bsrc;
    float s = 0.f;
    #pragma unroll
    for (int d = 0; d < 16; d++) s += attn[r*32 + side*16 + d] * b[r*16 + d];
    Cc[t] = s;
  }
  if (t < NBUK) bCur[t] = 0;
}

// ---------------- mega: fused partition | gemm_hs(+el) | gemm_er  (R12 champion)
__global__ __launch_bounds__(256) void mega(
    const float* __restrict__ feat_src, const float* __restrict__ feat_dst,
    const short* __restrict__ Wbf, const short* __restrict__ Ubf,
    const float* __restrict__ bias, const float* __restrict__ attn,
    const float* __restrict__ Cc,
    const int* __restrict__ src, const int* __restrict__ dst,
    int* __restrict__ bCur, unsigned* __restrict__ bData,
    __hip_bfloat16* __restrict__ hsC, float* __restrict__ el,
    float* __restrict__ er) {
  __shared__ __align__(16) char smem[20480];
  int b = blockIdx.x;
  int t = threadIdx.x;

  if (b < NPB) {
    // ---- edge partition ----
    int* h   = (int*)smem;
    int* cur = (int*)(smem + 2048);
    for (int i = t; i < NBUK; i += 256) h[i] = 0;
    __syncthreads();
    int start = b * EPB;
    int end = min(start + EPB, N_EDG);
    for (int e = start + t; e < end; e += 256)
      atomicAdd(&h[dst[e] / DPB], 1);
    __syncthreads();
    for (int i = t; i < NBUK; i += 256) {
      int c = h[i];
      cur[i] = c ? atomicAdd(&bCur[i], c) : 0;
    }
    __syncthreads();
    for (int e = start + t; e < end; e += 256) {
      int d = dst[e], bk = d / DPB;
      int pos = atomicAdd(&cur[bk], 1);
      if (pos < BCAP)
        bData[(size_t)bk*BCAP + pos] = (unsigned)src[e] | ((unsigned)(d - bk*DPB) << 16);
    }
    return;
  }

  if (b < NPB + GEMB) {
    // ---- hs gemm (128-row tile, 4 waves 2x2) + fused el, reg-prefetched ----
    short (*As)[40] = (short(*)[40])smem;
    short (*Bs)[40] = (short(*)[40])(smem + 10240);
    int lane = t & 63, wid = t >> 6;
    int wr = wid >> 1, wc = wid & 1;
    int row0 = (b - NPB) * 128;
    int lr = lane & 15, lk = lane >> 4;
    int sr = t >> 1, skq = (t & 1) * 16;
    int gr = row0 + sr;
    f32x4 acc[4][4] = {};
    float4 pa0 = {}, pa1 = {}, pa2 = {}, pa3 = {};
    bf16x8 pb0, pb1;

    #define LOADA_HS(K0) { \
      if (gr < N_SRCC) { \
        const float4* p = (const float4*)&feat_src[(size_t)gr*256 + (K0) + skq]; \
        pa0 = p[0]; pa1 = p[1]; pa2 = p[2]; pa3 = p[3]; \
      } \
    }
    #define LOADB_HS(K0) { \
      pb0 = *(const bf16x8*)&Wbf[sr*256 + (K0) + skq]; \
      pb1 = *(const bf16x8*)&Wbf[sr*256 + (K0) + skq + 8]; \
    }

    LOADA_HS(0); LOADB_HS(0);
    for (int k0 = 0; k0 < 256; k0 += 32) {
      {
        bf16x8 t0, t1;
        t0[0]=f2bf(pa0.x); t0[1]=f2bf(pa0.y); t0[2]=f2bf(pa0.z); t0[3]=f2bf(pa0.w);
        t0[4]=f2bf(pa1.x); t0[5]=f2bf(pa1.y); t0[6]=f2bf(pa1.z); t0[7]=f2bf(pa1.w);
        t1[0]=f2bf(pa2.x); t1[1]=f2bf(pa2.y); t1[2]=f2bf(pa2.z); t1[3]=f2bf(pa2.w);
        t1[4]=f2bf(pa3.x); t1[5]=f2bf(pa3.y); t1[6]=f2bf(pa3.z); t1[7]=f2bf(pa3.w);
        *(bf16x8*)&As[sr][skq]     = t0;
        *(bf16x8*)&As[sr][skq + 8] = t1;
        *(bf16x8*)&Bs[sr][skq]     = pb0;
        *(bf16x8*)&Bs[sr][skq + 8] = pb1;
      }
      __syncthreads();
      if (k0 < 224) { LOADA_HS(k0 + 32); LOADB_HS(k0 + 32); }
      bf16x8 af[4], bfr[4];
      #pragma unroll
      for (int m = 0; m < 4; m++)
        af[m] = *(const bf16x8*)&As[wr*64 + m*16 + lr][lk*8];
      #pragma unroll
      for (int n = 0; n < 4; n++)
        bfr[n] = *(const bf16x8*)&Bs[wc*64 + n*16 + lr][lk*8];
      #pragma unroll
      for (int m = 0; m < 4; m++)
        #pragma unroll
        for (int n = 0; n < 4; n++)
          acc[m][n] = __builtin_amdgcn_mfma_f32_16x16x32_bf16(af[m], bfr[n], acc[m][n], 0, 0, 0);
      __syncthreads();
    }
    #undef LOADA_HS
    #undef LOADB_HS
    #pragma unroll
    for (int m = 0; m < 4; m++) {
      int r0 = row0 + wr*64 + m*16 + lk*4;
      #pragma unroll
      for (int n = 0; n < 4; n++) {
        int col = wc*64 + n*16 + lr;
        int h = wc*4 + n;
        float bv = bias[col];
        float al = attn[h*32 + lr];
        #pragma unroll
        for (int j = 0; j < 4; j++) {
          int gr2 = r0 + j;
          float hv = acc[m][n][j] + bv;
          if (gr2 < N_SRCC) hsC[(size_t)gr2*128 + col] = __float2bfloat16(hv);
          float p = hv * al;
          p += __shfl_xor(p, 1); p += __shfl_xor(p, 2);
          p += __shfl_xor(p, 4); p += __shfl_xor(p, 8);
          if (lr == 0 && gr2 < N_SRCC) el[gr2*8 + h] = p;
        }
      }
    }
    return;
  }

  // ---- er gemm: feat_dst (128-row tile) @ Ubf^T (16 cols), reg-prefetched ----
  {
    short (*As)[40]  = (short(*)[40])smem;
    short (*Bu)[264] = (short(*)[264])(smem + 10240);
    int lane = t & 63, wid = t >> 6;     // wave owns 32 rows
    int row0 = (b - NPB - GEMB) * 128;
    int lr = lane & 15, lk = lane >> 4;
    int sr = t >> 1, skq = (t & 1) * 16;
    int gr = row0 + sr;
    #pragma unroll
    for (int i = 0; i < 2; i++) {
      int c = t + i*256;
      int r = c >> 5, ck = c & 31;
      *(bf16x8*)&Bu[r][ck*8] = *(const bf16x8*)&Ubf[r*256 + ck*8];
    }
    f32x4 acc[2] = {};
    float4 pa0 = {}, pa1 = {}, pa2 = {}, pa3 = {};

    #define LOADA_ER(K0) { \
      if (gr < N_DSTC) { \
        const float4* p = (const float4*)&feat_dst[(size_t)gr*256 + (K0) + skq]; \
        pa0 = p[0]; pa1 = p[1]; pa2 = p[2]; pa3 = p[3]; \
      } \
    }

    LOADA_ER(0);
    for (int k0 = 0; k0 < 256; k0 += 32) {
      {
        bf16x8 t0, t1;
        t0[0]=f2bf(pa0.x); t0[1]=f2bf(pa0.y); t0[2]=f2bf(pa0.z); t0[3]=f2bf(pa0.w);
        t0[4]=f2bf(pa1.x); t0[5]=f2bf(pa1.y); t0[6]=f2bf(pa1.z); t0[7]=f2bf(pa1.w);
        t1[0]=f2bf(pa2.x); t1[1]=f2bf(pa2.y); t1[2]=f2bf(pa2.z); t1[3]=f2bf(pa2.w);
        t1[4]=f2bf(pa3.x); t1[5]=f2bf(pa3.y); t1[6]=f2bf(pa3.z); t1[7]=f2bf(pa3.w);
        *(bf16x8*)&As[sr][skq]     = t0;
        *(bf16x8*)&As[sr][skq + 8] = t1;
      }
      __syncthreads();
      if (k0 < 224) LOADA_ER(k0 + 32);
      bf16x8 bu = *(const bf16x8*)&Bu[lr][k0 + lk*8];
      #pragma unroll
      for (int m = 0; m < 2; m++) {
        bf16x8 af = *(const bf16x8*)&As[wid*32 + m*16 + lr][lk*8];
        acc[m] = __builtin_amdgcn_mfma_f32_16x16x32_bf16(af, bu, acc[m], 0, 0, 0);
      }
      __syncthreads();
    }
    #undef LOADA_ER
    if (lr < 8) {
      float cb = Cc[8 + lr];
      #pragma unroll
      for (int m = 0; m < 2; m++) {
        int r0 = row0 + wid*32 + m*16 + lk*4;
        #pragma unroll
        for (int j = 0; j < 4; j++) {
          int gr2 = r0 + j;
          if (gr2 < N_DSTC) er[gr2*8 + lr] = acc[m][j] + cb;
        }
      }
    }
  }
}

// ---------------- sortagg: one block per bucket. Phase 1: counting sort in LDS.
// Phase 2: 8 waves aggregate the bucket's 100 dsts (2-list interleave).
__global__ __launch_bounds__(512) void sortagg(
    const unsigned* __restrict__ bData, const int* __restrict__ bCur,
    const __hip_bfloat16* __restrict__ hs, const float* __restrict__ el,
    const float* __restrict__ er, float* __restrict__ out) {
  __shared__ int hist[DPB];
  __shared__ int scan[128];
  __shared__ int offs[DPB + 1];
  __shared__ unsigned short srcL[BCAP];   // 4 KB
  int b = blockIdx.x, t = threadIdx.x;
  int cnt = min(bCur[b], BCAP);
  int base = b * BCAP;

  // ---- phase 1: sort bucket into srcL ----
  for (int i = t; i < DPB; i += 512) hist[i] = 0;
  __syncthreads();
  for (int e = t; e < cnt; e += 512) atomicAdd(&hist[bData[base + e] >> 16], 1);
  __syncthreads();
  if (t < 128) scan[t] = (t < DPB) ? hist[t] : 0;
  __syncthreads();
  for (int d = 1; d < 128; d <<= 1) {
    int v = (t < 128 && t >= d) ? scan[t - d] : 0;
    __syncthreads();
    if (t < 128) scan[t] += v;
    __syncthreads();
  }
  if (t < DPB) offs[t] = scan[t] - hist[t];   // exclusive prefix
  if (t == 0) offs[DPB] = cnt;
  __syncthreads();
  if (t < DPB) hist[t] = offs[t];             // reuse hist as scatter cursor
  __syncthreads();
  for (int e = t; e < cnt; e += 512) {
    unsigned ent = bData[base + e];
    int pos = atomicAdd(&hist[ent >> 16], 1);
    srcL[pos] = (unsigned short)(ent & 0xffffu);
  }
  __syncthreads();

  // ---- phase 2: aggregate. wave w handles dst pairs (p, p+50), p = w, w+8, ... ----
  int w = t >> 6, lane = t & 63;
  int g = lane >> 4;        // edge slot 0..3
  int q = lane & 15;        // channel group: channels q*8..q*8+7
  int h = q >> 1;           // head
  int d0 = b * DPB;

  for (int p = w; p < 50; p += 8) {
    int dA = p, dB = p + 50;
    int jA = d0 + dA, jB = d0 + dB;
    int e0a = offs[dA], remA = offs[dA + 1] - e0a;
    int e0b = offs[dB], remB = offs[dB + 1] - e0b;
    float erA = er[jA*8 + h];
    float erB = er[jB*8 + h];
    float accA[8] = {}, accB[8] = {};
    float denA = 0.f, denB = 0.f;

    #define AGG_BODY(E, ERH, ACC, DEN) { \
      int s = srcL[E]; \
      float ev = el[s*8 + h] + ERH; \
      ev = ev >= 0.f ? ev : 0.2f * ev; \
      float wg = __expf(ev); \
      DEN += wg; \
      us8 hv = *(const us8*)&hs[(size_t)s*128 + q*8]; \
      _Pragma("unroll") \
      for (int c = 0; c < 8; c++) { \
        ACC[c] = fmaf(wg, bf2f((unsigned)hv[c]), ACC[c]); \
      } \
    }

    int ka = 0, kb = 0;
    while (ka + 8 <= remA && kb + 8 <= remB) {
      AGG_BODY(e0a + ka + g, erA, accA, denA);
      AGG_BODY(e0b + kb + g, erB, accB, denB);
      AGG_BODY(e0a + ka + 4 + g, erA, accA, denA);
      AGG_BODY(e0b + kb + 4 + g, erB, accB, denB);
      ka += 8; kb += 8;
    }
    while (ka + 4 <= remA && kb + 4 <= remB) {
      AGG_BODY(e0a + ka + g, erA, accA, denA);
      AGG_BODY(e0b + kb + g, erB, accB, denB);
      ka += 4; kb += 4;
    }
    while (ka + 4 <= remA) { AGG_BODY(e0a + ka + g, erA, accA, denA); ka += 4; }
    while (kb + 4 <= remB) { AGG_BODY(e0b + kb + g, erB, accB, denB); kb += 4; }
    if (ka + g < remA) AGG_BODY(e0a + ka + g, erA, accA, denA);
    if (kb + g < remB) AGG_BODY(e0b + kb + g, erB, accB, denB);
    #undef AGG_BODY

    #pragma unroll
    for (int c = 0; c < 8; c++) {
      accA[c] += __shfl_xor(accA[c], 16); accA[c] += __shfl_xor(accA[c], 32);
      accB[c] += __shfl_xor(accB[c], 16); accB[c] += __shfl_xor(accB[c], 32);
    }
    denA += __shfl_xor(denA, 16); denA += __shfl_xor(denA, 32);
    denB += __shfl_xor(denB, 16); denB += __shfl_xor(denB, 32);
    if (g == 0) {
      float invA = (remA > 0) ? 1.f / denA : 0.f;
      float invB = (remB > 0) ? 1.f / denB : 0.f;
      float4 r0, r1;
      r0.x = accA[0]*invA; r0.y = accA[1]*invA; r0.z = accA[2]*invA; r0.w = accA[3]*invA;
      r1.x = accA[4]*invA; r1.y = accA[5]*invA; r1.z = accA[6]*invA; r1.w = accA[7]*invA;
      *(float4*)&out[(size_t)jA*128 + q*8]     = r0;
      *(float4*)&out[(size_t)jA*128 + q*8 + 4] = r1;
      r0.x = accB[0]*invB; r0.y = accB[1]*invB; r0.z = accB[2]*invB; r0.w = accB[3]*invB;
      r1.x = accB[4]*invB; r1.y = accB[5]*invB; r1.z = accB[6]*invB; r1.w = accB[7]*invB;
      *(float4*)&out[(size_t)jB*128 + q*8]     = r0;
      *(float4*)&out[(size_t)jB*128 + q*8 + 4] = r1;
    }
  }
}

extern "C" void kernel_launch(void* const* d_in, const int* in_sizes, int n_in,
                              void* d_out, int out_size, void* d_ws, size_t ws_size,
                              hipStream_t stream) {
  const float* feat_src = (const float*)d_in[0];
  const float* feat_dst = (const float*)d_in[1];
  const float* W_src = (const float*)d_in[2];
  const float* b_src = (const float*)d_in[3];
  const float* W_dst = (const float*)d_in[4];
  const float* b_dst = (const float*)d_in[5];
  const float* attn  = (const float*)d_in[6];
  const int* src_idx = (const int*)d_in[7];
  const int* dst_idx = (const int*)d_in[8];
  float* out = (float*)d_out;

  __hip_bfloat16* hs_bf = (__hip_bfloat16*)d_ws;        // 12.8 MB
  float* el = (float*)(hs_bf + (size_t)N_SRCC*128);     // 400,000 f
  float* er = el + (size_t)N_SRCC*8;                    // 400,000 f
  float* U  = er + (size_t)N_DSTC*8;                    // 4096 f
  float* Cc = U + 4096;                                 // 16 f
  short* Wbf = (short*)(Cc + 16);                       // 32768 bf16
  short* Ubf = Wbf + 32768;                             // 4096 bf16 (16x256)
  int* bCur  = (int*)(Ubf + 4096);                      // 500 i
  unsigned* bData = (unsigned*)(bCur + NBUK);           // 500*2048 u32

  fold_kernel<<<16, 256, 0, stream>>>(W_src, b_src, W_dst, b_dst, attn, U, Cc,
                                      Wbf, Ubf, bCur);
  mega<<<NPB + 2*GEMB, 256, 0, stream>>>(feat_src, feat_dst, Wbf, Ubf, b_src, attn,
                                         Cc, src_idx, dst_idx, bCur, bData,
                                         hs_bf, el, er);
  sortagg<<<NBUK, 512, 0, stream>>>(bData, bCur, hs_bf, el, er, out);
}